// Round 1
// baseline (588.058 us; speedup 1.0000x reference)
//
#include <hip/hip_runtime.h>
#include <math.h>

#define B_SZ   256
#define D_IN   2048
#define HID    2048
#define NSEG   10
#define D_CTX  1024
#define OUT_N  100
#define KWIN   102
#define CAP    256   // max compacted nnz per row (nnz ~51/102, +many sigma safe)

// ---------- sortable-key helpers for exact fp32 top-k ----------
__device__ __forceinline__ unsigned f2key(float f) {
  unsigned b = __float_as_uint(f);
  return (b & 0x80000000u) ? ~b : (b | 0x80000000u);  // descending float == descending key
}
__device__ __forceinline__ float key2f(unsigned k) {
  return (k & 0x80000000u) ? __uint_as_float(k & 0x7FFFFFFFu) : __uint_as_float(~k);
}

// ---------- tiled transpose: dst[c][r] = src[r][c]; rows,cols multiples of 32 ----------
__global__ __launch_bounds__(256) void transpose_k(const float* __restrict__ src,
                                                   float* __restrict__ dst,
                                                   int rows, int cols) {
  __shared__ float tile[32][33];
  int c0 = blockIdx.x * 32, r0 = blockIdx.y * 32;
  int tx = threadIdx.x, ty = threadIdx.y;
  for (int i = ty; i < 32; i += 8)
    tile[i][tx] = src[(r0 + i) * cols + (c0 + tx)];
  __syncthreads();
  for (int i = ty; i < 32; i += 8)
    dst[(c0 + i) * rows + (r0 + tx)] = tile[tx][i];
}

// ---------- in-block compaction of one masked row into LDS (val, idx) pairs ----------
__device__ __forceinline__ int compact_seg(const float* __restrict__ wrow,
                                           const float* __restrict__ mrow,
                                           int len4, float2* pairs, int* scnt) {
  const int t = threadIdx.x;
  if (t == 0) *scnt = 0;
  __syncthreads();  // also protects pairs[] against previous gather's readers
  const float4* __restrict__ w4 = (const float4*)wrow;
  const float4* __restrict__ m4 = (const float4*)mrow;
  for (int e = t; e < len4; e += 64) {
    float4 w = w4[e];
    float4 m = m4[e];
    bool n0 = (m.x != 0.f), n1 = (m.y != 0.f), n2 = (m.z != 0.f), n3 = (m.w != 0.f);
    int nz = (int)n0 + (int)n1 + (int)n2 + (int)n3;
    if (nz) {
      int pos = atomicAdd(scnt, nz);
      int c = e << 2;
      if (n0) { if (pos < CAP) pairs[pos] = make_float2(w.x, __int_as_float(c));     pos++; }
      if (n1) { if (pos < CAP) pairs[pos] = make_float2(w.y, __int_as_float(c + 1)); pos++; }
      if (n2) { if (pos < CAP) pairs[pos] = make_float2(w.z, __int_as_float(c + 2)); pos++; }
      if (n3) { if (pos < CAP) pairs[pos] = make_float2(w.w, __int_as_float(c + 3)); pos++; }
    }
  }
  __syncthreads();
  int c = *scnt;
  return c > CAP ? CAP : c;
}

// ---------- sparse dot: out4[i] = sum_j val_j * src[idx_j*256 + 4t + i] ----------
__device__ __forceinline__ void gather_dot(const float* __restrict__ src,
                                           const float2* pairs, int cnt,
                                           int t4, float out4[4]) {
  float acc[4][4];
#pragma unroll
  for (int s = 0; s < 4; ++s)
#pragma unroll
    for (int i = 0; i < 4; ++i) acc[s][i] = 0.f;
  int j = 0;
  for (; j + 4 <= cnt; j += 4) {
#pragma unroll
    for (int s = 0; s < 4; ++s) {
      float2 p = pairs[j + s];
      const float4 cv = *(const float4*)(src + (__float_as_int(p.y) << 8) + t4);
      acc[s][0] += cv.x * p.x; acc[s][1] += cv.y * p.x;
      acc[s][2] += cv.z * p.x; acc[s][3] += cv.w * p.x;
    }
  }
  for (; j < cnt; ++j) {
    float2 p = pairs[j];
    const float4 cv = *(const float4*)(src + (__float_as_int(p.y) << 8) + t4);
    acc[0][0] += cv.x * p.x; acc[0][1] += cv.y * p.x;
    acc[0][2] += cv.z * p.x; acc[0][3] += cv.w * p.x;
  }
#pragma unroll
  for (int i = 0; i < 4; ++i)
    out4[i] = (acc[0][i] + acc[1][i]) + (acc[2][i] + acc[3][i]);
}

// ---------- dendrite kernel: bid<HID -> layer1 (FF1 + gates1 -> y1T); else gates2 -> gate2T ----------
__global__ __launch_bounds__(64) void dend_kernel(
    const float* __restrict__ W1, const float* __restrict__ maskW1, const float* __restrict__ b1,
    const float* __restrict__ segW1, const float* __restrict__ maskS1,
    const float* __restrict__ segW2, const float* __restrict__ maskS2,
    const float* __restrict__ xT, const float* __restrict__ ctxT,
    float* __restrict__ y1T, float* __restrict__ gate2T) {
  __shared__ float2 pairs[CAP];
  __shared__ int scnt;
  const int t = threadIdx.x, t4 = t * 4;
  const int bid = blockIdx.x;
  float bestA[4] = {-1.f, -1.f, -1.f, -1.f};
  float chosen[4] = {0.f, 0.f, 0.f, 0.f};

  if (bid < HID) {
    const int u = bid;
    int cnt = compact_seg(W1 + u * D_IN, maskW1 + u * D_IN, D_IN / 4, pairs, &scnt);
    float ff[4];
    gather_dot(xT, pairs, cnt, t4, ff);
    for (int s = 0; s < NSEG; ++s) {
      const int r = (u * NSEG + s) * D_CTX;
      cnt = compact_seg(segW1 + r, maskS1 + r, D_CTX / 4, pairs, &scnt);
      float d[4];
      gather_dot(ctxT, pairs, cnt, t4, d);
#pragma unroll
      for (int i = 0; i < 4; ++i) {
        float a = fabsf(d[i]);
        if (a > bestA[i]) { bestA[i] = a; chosen[i] = d[i]; }  // strict > == first-occurrence argmax
      }
    }
    float bb = b1[u];
    float4 o;
    o.x = (ff[0] + bb) / (1.f + expf(-chosen[0]));
    o.y = (ff[1] + bb) / (1.f + expf(-chosen[1]));
    o.z = (ff[2] + bb) / (1.f + expf(-chosen[2]));
    o.w = (ff[3] + bb) / (1.f + expf(-chosen[3]));
    *(float4*)(y1T + u * B_SZ + t4) = o;
  } else {
    const int u = bid - HID;
    for (int s = 0; s < NSEG; ++s) {
      const int r = (u * NSEG + s) * D_CTX;
      int cnt = compact_seg(segW2 + r, maskS2 + r, D_CTX / 4, pairs, &scnt);
      float d[4];
      gather_dot(ctxT, pairs, cnt, t4, d);
#pragma unroll
      for (int i = 0; i < 4; ++i) {
        float a = fabsf(d[i]);
        if (a > bestA[i]) { bestA[i] = a; chosen[i] = d[i]; }
      }
    }
    float4 g;
    g.x = 1.f / (1.f + expf(-chosen[0]));
    g.y = 1.f / (1.f + expf(-chosen[1]));
    g.z = 1.f / (1.f + expf(-chosen[2]));
    g.w = 1.f / (1.f + expf(-chosen[3]));
    *(float4*)(gate2T + u * B_SZ + t4) = g;
  }
}

// ---------- FF2: y2T[u][b] = (sum_c h1T[c][b]*W2m[u,c] + b2[u]) * gate2T[u][b] ----------
__global__ __launch_bounds__(64) void ff2_kernel(
    const float* __restrict__ W2, const float* __restrict__ maskW2, const float* __restrict__ b2,
    const float* __restrict__ h1T, const float* __restrict__ gate2T, float* __restrict__ y2T) {
  __shared__ float2 pairs[CAP];
  __shared__ int scnt;
  const int t = threadIdx.x, t4 = t * 4, u = blockIdx.x;
  int cnt = compact_seg(W2 + u * HID, maskW2 + u * HID, HID / 4, pairs, &scnt);
  float acc[4];
  gather_dot(h1T, pairs, cnt, t4, acc);
  float bb = b2[u];
  float4 g = *(const float4*)(gate2T + u * B_SZ + t4);
  float4 o;
  o.x = (acc[0] + bb) * g.x; o.y = (acc[1] + bb) * g.y;
  o.z = (acc[2] + bb) * g.z; o.w = (acc[3] + bb) * g.w;
  *(float4*)(y2T + u * B_SZ + t4) = o;
}

// ---------- exact top-K per batch row via 4x8bit radix select; stable index-order ties ----------
// mode 0: dst is hT [HID][B]; mode 1: dst is h rows [B][HID]
__global__ __launch_bounds__(256) void topk_kernel(const float* __restrict__ yT,
                                                   float* __restrict__ dst, int mode) {
  const int b = blockIdx.x, t = threadIdx.x;
  __shared__ int hist[256];
  __shared__ int sfx[256];
  __shared__ unsigned sPref;
  __shared__ int sRem;
  unsigned myk[8];
#pragma unroll
  for (int i = 0; i < 8; ++i) {
    int u = t * 8 + i;  // contiguous chunk per thread -> natural index order for tie-break
    myk[i] = f2key(yT[u * B_SZ + b]);
  }
  unsigned pref = 0;
  int rem = KWIN;
  for (int shift = 24; shift >= 0; shift -= 8) {
    hist[t] = 0;
    __syncthreads();
    unsigned hiMask = (shift == 24) ? 0u : (0xFFFFFFFFu << (shift + 8));
#pragma unroll
    for (int i = 0; i < 8; ++i) {
      unsigned k = myk[i];
      if ((k & hiMask) == pref) atomicAdd(&hist[(k >> shift) & 255], 1);
    }
    __syncthreads();
    sfx[t] = hist[t];
    __syncthreads();
    for (int off = 1; off < 256; off <<= 1) {
      int add = (t + off < 256) ? sfx[t + off] : 0;
      __syncthreads();
      sfx[t] += add;
      __syncthreads();
    }
    int s_incl = sfx[t];
    int s_excl = (t == 255) ? 0 : sfx[t + 1];
    if (s_incl >= rem && s_excl < rem) {  // unique winner bin
      sPref = pref | (((unsigned)t) << shift);
      sRem = rem - s_excl;
    }
    __syncthreads();
    pref = sPref;
    rem = sRem;
    __syncthreads();
  }
  // exact index-order tie-break among keys == pref: keep first `rem`
  int eq = 0;
#pragma unroll
  for (int i = 0; i < 8; ++i) eq += (myk[i] == pref) ? 1 : 0;
  sfx[t] = eq;
  __syncthreads();
  for (int off = 1; off < 256; off <<= 1) {
    int add = (t >= off) ? sfx[t - off] : 0;
    __syncthreads();
    sfx[t] += add;
    __syncthreads();
  }
  int excl = sfx[t] - eq;
  int taken = 0;
#pragma unroll
  for (int i = 0; i < 8; ++i) {
    unsigned k = myk[i];
    bool keep;
    if (k > pref) keep = true;
    else if (k == pref) { keep = (excl + taken) < rem; taken++; }
    else keep = false;
    float f = keep ? key2f(k) : 0.f;
    int u = t * 8 + i;
    if (mode == 0) dst[u * B_SZ + b] = f;
    else dst[b * HID + u] = f;
  }
}

// ---------- Dale output head: out[b,o] = h2.Wex[o] - Wei[o]*(h2.Wix) + b_out[o] ----------
__global__ __launch_bounds__(256) void out_kernel(
    const float* __restrict__ h2, const float* __restrict__ Wex, const float* __restrict__ Wix,
    const float* __restrict__ Wei, const float* __restrict__ bo, float* __restrict__ out) {
  const int b = blockIdx.x, t = threadIdx.x;
  __shared__ float hrow[HID];
  __shared__ float red[256];
  float part = 0.f;
#pragma unroll
  for (int i = 0; i < 8; ++i) {
    int u = t + 256 * i;
    float v = h2[b * HID + u];
    hrow[u] = v;
    part += v * Wix[u];
  }
  red[t] = part;
  __syncthreads();
  for (int off = 128; off > 0; off >>= 1) {
    if (t < off) red[t] += red[t + off];
    __syncthreads();
  }
  float S = red[0];
  const int w = t >> 6, l = t & 63;
  for (int o = w; o < OUT_N; o += 4) {
    float acc = 0.f;
    const float* wr = Wex + o * HID;
#pragma unroll
    for (int q = 0; q < HID / 64; ++q) acc += hrow[l + 64 * q] * wr[l + 64 * q];
    for (int off = 32; off > 0; off >>= 1) acc += __shfl_down(acc, off, 64);
    if (l == 0) out[b * OUT_N + o] = acc - Wei[o] * S + bo[o];
  }
}

extern "C" void kernel_launch(void* const* d_in, const int* in_sizes, int n_in,
                              void* d_out, int out_size, void* d_ws, size_t ws_size,
                              hipStream_t stream) {
  const float* x      = (const float*)d_in[0];
  const float* ctx    = (const float*)d_in[1];
  const float* W1     = (const float*)d_in[2];
  const float* b1     = (const float*)d_in[3];
  const float* segW1  = (const float*)d_in[4];
  const float* maskW1 = (const float*)d_in[5];
  const float* maskS1 = (const float*)d_in[6];
  const float* W2     = (const float*)d_in[7];
  const float* b2     = (const float*)d_in[8];
  const float* segW2  = (const float*)d_in[9];
  const float* maskW2 = (const float*)d_in[10];
  const float* maskS2 = (const float*)d_in[11];
  const float* Wex    = (const float*)d_in[12];
  const float* Wix    = (const float*)d_in[13];
  const float* Wei    = (const float*)d_in[14];
  const float* bo     = (const float*)d_in[15];
  float* out = (float*)d_out;
  float* ws = (float*)d_ws;

  float* xT     = ws;             // 2048*256
  float* ctxT   = ws + 524288;    // 1024*256
  float* y1T    = ws + 786432;    // 2048*256
  float* gate2T = ws + 1310720;   // 2048*256
  float* h1T    = ws + 1835008;   // 2048*256
  float* y2T    = ws + 2359296;   // 2048*256
  float* h2     = ws + 2883584;   // 256*2048   (total ~13 MB of ws)

  dim3 tb(32, 8);
  transpose_k<<<dim3(D_IN / 32, B_SZ / 32), tb, 0, stream>>>(x, xT, B_SZ, D_IN);
  transpose_k<<<dim3(D_CTX / 32, B_SZ / 32), tb, 0, stream>>>(ctx, ctxT, B_SZ, D_CTX);
  dend_kernel<<<2 * HID, 64, 0, stream>>>(W1, maskW1, b1, segW1, maskS1, segW2, maskS2,
                                          xT, ctxT, y1T, gate2T);
  topk_kernel<<<B_SZ, 256, 0, stream>>>(y1T, h1T, 0);
  ff2_kernel<<<HID, 64, 0, stream>>>(W2, maskW2, b2, h1T, gate2T, y2T);
  topk_kernel<<<B_SZ, 256, 0, stream>>>(y2T, h2, 1);
  out_kernel<<<B_SZ, 256, 0, stream>>>(h2, Wex, Wix, Wei, bo, out);
}

// Round 2
// 519.945 us; speedup vs baseline: 1.1310x; 1.1310x over previous
//
#include <hip/hip_runtime.h>
#include <math.h>

#define B_SZ   256
#define D_IN   2048
#define HID    2048
#define NSEG   10
#define D_CTX  1024
#define OUT_N  100
#define KWIN   102
#define CAP    256   // max compacted nnz per row (mean 51/102, +many sigma safe)

typedef float f32x4 __attribute__((ext_vector_type(4)));

// non-temporal 16B load: keeps weight/mask streams from evicting L2-resident activations
__device__ __forceinline__ f32x4 ntld4(const float* p) {
  return __builtin_nontemporal_load((const f32x4*)p);
}

// ---------- sortable-key helpers for exact fp32 top-k ----------
__device__ __forceinline__ unsigned f2key(float f) {
  unsigned b = __float_as_uint(f);
  return (b & 0x80000000u) ? ~b : (b | 0x80000000u);
}
__device__ __forceinline__ float key2f(unsigned k) {
  return (k & 0x80000000u) ? __uint_as_float(k & 0x7FFFFFFFu) : __uint_as_float(~k);
}

// ---------- tiled transpose: dst[c][r] = src[r][c]; rows,cols multiples of 32 ----------
__global__ __launch_bounds__(256) void transpose_k(const float* __restrict__ src,
                                                   float* __restrict__ dst,
                                                   int rows, int cols) {
  __shared__ float tile[32][33];
  int c0 = blockIdx.x * 32, r0 = blockIdx.y * 32;
  int tx = threadIdx.x, ty = threadIdx.y;
  for (int i = ty; i < 32; i += 8)
    tile[i][tx] = src[(r0 + i) * cols + (c0 + tx)];
  __syncthreads();
  for (int i = ty; i < 32; i += 8)
    dst[(c0 + i) * rows + (r0 + tx)] = tile[tx][i];
}

// ---------- per-wave compaction of one masked row into private LDS (val, idx) pairs ----------
// All waves in the block call this the same number of times (homogeneous blocks),
// so the __syncthreads() barriers stay aligned.
__device__ __forceinline__ int compact_seg(const float* __restrict__ wrow,
                                           const float* __restrict__ mrow,
                                           int len4, float2* pairs, int* scnt) {
  const int t = threadIdx.x & 63;
  if (t == 0) *scnt = 0;
  __syncthreads();
  for (int e = t; e < len4; e += 64) {
    f32x4 w = ntld4(wrow + 4 * e);
    f32x4 m = ntld4(mrow + 4 * e);
    bool n0 = (m.x != 0.f), n1 = (m.y != 0.f), n2 = (m.z != 0.f), n3 = (m.w != 0.f);
    int nz = (int)n0 + (int)n1 + (int)n2 + (int)n3;
    if (nz) {
      int pos = atomicAdd(scnt, nz);
      int c = e << 2;
      if (n0) { if (pos < CAP) pairs[pos] = make_float2(w.x, __int_as_float(c));     pos++; }
      if (n1) { if (pos < CAP) pairs[pos] = make_float2(w.y, __int_as_float(c + 1)); pos++; }
      if (n2) { if (pos < CAP) pairs[pos] = make_float2(w.z, __int_as_float(c + 2)); pos++; }
      if (n3) { if (pos < CAP) pairs[pos] = make_float2(w.w, __int_as_float(c + 3)); pos++; }
    }
  }
  __syncthreads();
  int c = *scnt;
  return c > CAP ? CAP : c;
}

// ---------- sparse dot, unroll-8 (8 outstanding 1KB loads/wave) ----------
__device__ __forceinline__ void gather_dot(const float* __restrict__ src,
                                           const float2* pairs, int cnt,
                                           int t4, float out4[4]) {
  float acc[4][4];
#pragma unroll
  for (int s = 0; s < 4; ++s)
#pragma unroll
    for (int i = 0; i < 4; ++i) acc[s][i] = 0.f;
  int j = 0;
  for (; j + 8 <= cnt; j += 8) {
#pragma unroll
    for (int s = 0; s < 8; ++s) {
      float2 p = pairs[j + s];
      const f32x4 cv = *(const f32x4*)(src + (__float_as_int(p.y) << 8) + t4);
      acc[s & 3][0] += cv.x * p.x; acc[s & 3][1] += cv.y * p.x;
      acc[s & 3][2] += cv.z * p.x; acc[s & 3][3] += cv.w * p.x;
    }
  }
  for (; j < cnt; ++j) {
    float2 p = pairs[j];
    const f32x4 cv = *(const f32x4*)(src + (__float_as_int(p.y) << 8) + t4);
    acc[0][0] += cv.x * p.x; acc[0][1] += cv.y * p.x;
    acc[0][2] += cv.z * p.x; acc[0][3] += cv.w * p.x;
  }
#pragma unroll
  for (int i = 0; i < 4; ++i)
    out4[i] = (acc[0][i] + acc[1][i]) + (acc[2][i] + acc[3][i]);
}

// ---------- dendrite kernel: 4 waves/block, one row per wave ----------
// rows 0..HID-1   : layer1 (FF1 + gates1 -> y1T)  [blocks 0..511, homogeneous: 11 compacts]
// rows HID..2HID-1: layer2 gates -> gate2T         [blocks 512..1023: 10 compacts]
__global__ __launch_bounds__(256, 4) void dend_kernel(
    const float* __restrict__ W1, const float* __restrict__ maskW1, const float* __restrict__ b1,
    const float* __restrict__ segW1, const float* __restrict__ maskS1,
    const float* __restrict__ segW2, const float* __restrict__ maskS2,
    const float* __restrict__ xT, const float* __restrict__ ctxT,
    float* __restrict__ y1T, float* __restrict__ gate2T) {
  __shared__ float2 pairs_s[4][CAP];
  __shared__ int scnt_s[4];
  const int wave = threadIdx.x >> 6;
  const int t = threadIdx.x & 63, t4 = t * 4;
  float2* pairs = pairs_s[wave];
  int* scnt = &scnt_s[wave];
  const int row = blockIdx.x * 4 + wave;

  float bestA[4] = {-1.f, -1.f, -1.f, -1.f};
  float chosen[4] = {0.f, 0.f, 0.f, 0.f};

  if (row < HID) {
    const int u = row;
    int cnt = compact_seg(W1 + u * D_IN, maskW1 + u * D_IN, D_IN / 4, pairs, scnt);
    float ff[4];
    gather_dot(xT, pairs, cnt, t4, ff);
    for (int s = 0; s < NSEG; ++s) {
      const int r = (u * NSEG + s) * D_CTX;
      cnt = compact_seg(segW1 + r, maskS1 + r, D_CTX / 4, pairs, scnt);
      float d[4];
      gather_dot(ctxT, pairs, cnt, t4, d);
#pragma unroll
      for (int i = 0; i < 4; ++i) {
        float a = fabsf(d[i]);
        if (a > bestA[i]) { bestA[i] = a; chosen[i] = d[i]; }  // strict > == first-occurrence argmax
      }
    }
    float bb = b1[u];
    float4 o;
    o.x = (ff[0] + bb) / (1.f + expf(-chosen[0]));
    o.y = (ff[1] + bb) / (1.f + expf(-chosen[1]));
    o.z = (ff[2] + bb) / (1.f + expf(-chosen[2]));
    o.w = (ff[3] + bb) / (1.f + expf(-chosen[3]));
    *(float4*)(y1T + u * B_SZ + t4) = o;
  } else {
    const int u = row - HID;
    for (int s = 0; s < NSEG; ++s) {
      const int r = (u * NSEG + s) * D_CTX;
      int cnt = compact_seg(segW2 + r, maskS2 + r, D_CTX / 4, pairs, scnt);
      float d[4];
      gather_dot(ctxT, pairs, cnt, t4, d);
#pragma unroll
      for (int i = 0; i < 4; ++i) {
        float a = fabsf(d[i]);
        if (a > bestA[i]) { bestA[i] = a; chosen[i] = d[i]; }
      }
    }
    float4 g;
    g.x = 1.f / (1.f + expf(-chosen[0]));
    g.y = 1.f / (1.f + expf(-chosen[1]));
    g.z = 1.f / (1.f + expf(-chosen[2]));
    g.w = 1.f / (1.f + expf(-chosen[3]));
    *(float4*)(gate2T + u * B_SZ + t4) = g;
  }
}

// ---------- FF2: 4 waves/block, one u per wave ----------
__global__ __launch_bounds__(256, 4) void ff2_kernel(
    const float* __restrict__ W2, const float* __restrict__ maskW2, const float* __restrict__ b2,
    const float* __restrict__ h1T, const float* __restrict__ gate2T, float* __restrict__ y2T) {
  __shared__ float2 pairs_s[4][CAP];
  __shared__ int scnt_s[4];
  const int wave = threadIdx.x >> 6;
  const int t = threadIdx.x & 63, t4 = t * 4;
  const int u = blockIdx.x * 4 + wave;
  int cnt = compact_seg(W2 + u * HID, maskW2 + u * HID, HID / 4, pairs_s[wave], &scnt_s[wave]);
  float acc[4];
  gather_dot(h1T, pairs_s[wave], cnt, t4, acc);
  float bb = b2[u];
  float4 g = *(const float4*)(gate2T + u * B_SZ + t4);
  float4 o;
  o.x = (acc[0] + bb) * g.x; o.y = (acc[1] + bb) * g.y;
  o.z = (acc[2] + bb) * g.z; o.w = (acc[3] + bb) * g.w;
  *(float4*)(y2T + u * B_SZ + t4) = o;
}

// ---------- exact top-K per row (in-place on [B][HID] rows, coalesced) ----------
__global__ __launch_bounds__(256) void topk_kernel(float* __restrict__ y) {
  const int b = blockIdx.x, t = threadIdx.x;
  __shared__ int hist[256];
  __shared__ int sfx[256];
  __shared__ unsigned sPref;
  __shared__ int sRem;
  float* __restrict__ row = y + b * HID;
  unsigned myk[8];
  f32x4 v0 = *(const f32x4*)(row + t * 8);
  f32x4 v1 = *(const f32x4*)(row + t * 8 + 4);
  myk[0] = f2key(v0.x); myk[1] = f2key(v0.y); myk[2] = f2key(v0.z); myk[3] = f2key(v0.w);
  myk[4] = f2key(v1.x); myk[5] = f2key(v1.y); myk[6] = f2key(v1.z); myk[7] = f2key(v1.w);
  unsigned pref = 0;
  int rem = KWIN;
  for (int shift = 24; shift >= 0; shift -= 8) {
    hist[t] = 0;
    __syncthreads();
    unsigned hiMask = (shift == 24) ? 0u : (0xFFFFFFFFu << (shift + 8));
#pragma unroll
    for (int i = 0; i < 8; ++i) {
      unsigned k = myk[i];
      if ((k & hiMask) == pref) atomicAdd(&hist[(k >> shift) & 255], 1);
    }
    __syncthreads();
    sfx[t] = hist[t];
    __syncthreads();
    for (int off = 1; off < 256; off <<= 1) {
      int add = (t + off < 256) ? sfx[t + off] : 0;
      __syncthreads();
      sfx[t] += add;
      __syncthreads();
    }
    int s_incl = sfx[t];
    int s_excl = (t == 255) ? 0 : sfx[t + 1];
    if (s_incl >= rem && s_excl < rem) {
      sPref = pref | (((unsigned)t) << shift);
      sRem = rem - s_excl;
    }
    __syncthreads();
    pref = sPref;
    rem = sRem;
    __syncthreads();
  }
  // exact index-order tie-break among keys == pref: keep first `rem`
  int eq = 0;
#pragma unroll
  for (int i = 0; i < 8; ++i) eq += (myk[i] == pref) ? 1 : 0;
  sfx[t] = eq;
  __syncthreads();
  for (int off = 1; off < 256; off <<= 1) {
    int add = (t >= off) ? sfx[t - off] : 0;
    __syncthreads();
    sfx[t] += add;
    __syncthreads();
  }
  int excl = sfx[t] - eq;
  int taken = 0;
  float o[8];
#pragma unroll
  for (int i = 0; i < 8; ++i) {
    unsigned k = myk[i];
    bool keep;
    if (k > pref) keep = true;
    else if (k == pref) { keep = (excl + taken) < rem; taken++; }
    else keep = false;
    o[i] = keep ? key2f(k) : 0.f;
  }
  f32x4 w0 = {o[0], o[1], o[2], o[3]};
  f32x4 w1 = {o[4], o[5], o[6], o[7]};
  *(f32x4*)(row + t * 8) = w0;
  *(f32x4*)(row + t * 8 + 4) = w1;
}

// ---------- Dale output head: out[b,o] = h2.Wex[o] - Wei[o]*(h2.Wix) + b_out[o] ----------
__global__ __launch_bounds__(256) void out_kernel(
    const float* __restrict__ h2, const float* __restrict__ Wex, const float* __restrict__ Wix,
    const float* __restrict__ Wei, const float* __restrict__ bo, float* __restrict__ out) {
  const int b = blockIdx.x, t = threadIdx.x;
  __shared__ float hrow[HID];
  __shared__ float red[256];
  float part = 0.f;
#pragma unroll
  for (int i = 0; i < 8; ++i) {
    int u = t + 256 * i;
    float v = h2[b * HID + u];
    hrow[u] = v;
    part += v * Wix[u];
  }
  red[t] = part;
  __syncthreads();
  for (int off = 128; off > 0; off >>= 1) {
    if (t < off) red[t] += red[t + off];
    __syncthreads();
  }
  float S = red[0];
  const int w = t >> 6, l = t & 63;
  for (int o = w; o < OUT_N; o += 4) {
    float acc = 0.f;
    const float* wr = Wex + o * HID;
#pragma unroll
    for (int q = 0; q < HID / 64; ++q) acc += hrow[l + 64 * q] * wr[l + 64 * q];
    for (int off = 32; off > 0; off >>= 1) acc += __shfl_down(acc, off, 64);
    if (l == 0) out[b * OUT_N + o] = acc - Wei[o] * S + bo[o];
  }
}

extern "C" void kernel_launch(void* const* d_in, const int* in_sizes, int n_in,
                              void* d_out, int out_size, void* d_ws, size_t ws_size,
                              hipStream_t stream) {
  const float* x      = (const float*)d_in[0];
  const float* ctx    = (const float*)d_in[1];
  const float* W1     = (const float*)d_in[2];
  const float* b1     = (const float*)d_in[3];
  const float* segW1  = (const float*)d_in[4];
  const float* maskW1 = (const float*)d_in[5];
  const float* maskS1 = (const float*)d_in[6];
  const float* W2     = (const float*)d_in[7];
  const float* b2     = (const float*)d_in[8];
  const float* segW2  = (const float*)d_in[9];
  const float* maskW2 = (const float*)d_in[10];
  const float* maskS2 = (const float*)d_in[11];
  const float* Wex    = (const float*)d_in[12];
  const float* Wix    = (const float*)d_in[13];
  const float* Wei    = (const float*)d_in[14];
  const float* bo     = (const float*)d_in[15];
  float* out = (float*)d_out;
  float* ws = (float*)d_ws;

  float* xT     = ws;             // 524288 floats
  float* ctxT   = ws + 524288;    // 262144
  float* y1T    = ws + 786432;    // 524288  (also reused as y2T)
  float* bufA   = ws + 1310720;   // 524288  (y1 -> h1 -> y2 -> h2, row-major)
  float* h1T    = ws + 1835008;   // 524288
  float* gate2T = ws + 2359296;   // 524288  (total ~11.5 MB)

  dim3 tb(32, 8);
  transpose_k<<<dim3(D_IN / 32, B_SZ / 32), tb, 0, stream>>>(x, xT, B_SZ, D_IN);
  transpose_k<<<dim3(D_CTX / 32, B_SZ / 32), tb, 0, stream>>>(ctx, ctxT, B_SZ, D_CTX);
  dend_kernel<<<2 * HID / 4, 256, 0, stream>>>(W1, maskW1, b1, segW1, maskS1, segW2, maskS2,
                                               xT, ctxT, y1T, gate2T);
  transpose_k<<<dim3(B_SZ / 32, HID / 32), tb, 0, stream>>>(y1T, bufA, HID, B_SZ);  // y1 rows
  topk_kernel<<<B_SZ, 256, 0, stream>>>(bufA);                                       // h1 rows
  transpose_k<<<dim3(HID / 32, B_SZ / 32), tb, 0, stream>>>(bufA, h1T, B_SZ, HID);  // h1T
  ff2_kernel<<<HID / 4, 256, 0, stream>>>(W2, maskW2, b2, h1T, gate2T, y1T);        // y2T
  transpose_k<<<dim3(B_SZ / 32, HID / 32), tb, 0, stream>>>(y1T, bufA, HID, B_SZ);  // y2 rows
  topk_kernel<<<B_SZ, 256, 0, stream>>>(bufA);                                       // h2 rows
  out_kernel<<<B_SZ, 256, 0, stream>>>(bufA, Wex, Wix, Wei, bo, out);
}

// Round 3
// 496.014 us; speedup vs baseline: 1.1856x; 1.0482x over previous
//
#include <hip/hip_runtime.h>
#include <math.h>

#define B_SZ   256
#define D_IN   2048
#define HID    2048
#define NSEG   10
#define D_CTX  1024
#define OUT_N  100
#define KWIN   102
#define CAP    256   // max compacted nnz per row (mean 102/51, +15 sigma safe)

typedef float f32x4 __attribute__((ext_vector_type(4)));

// non-temporal 16B load: weight/mask streams must not evict L2-resident activations
__device__ __forceinline__ f32x4 ntld4(const float* p) {
  return __builtin_nontemporal_load((const f32x4*)p);
}

// ---------- sortable-key helpers for exact fp32 top-k ----------
__device__ __forceinline__ unsigned f2key(float f) {
  unsigned b = __float_as_uint(f);
  return (b & 0x80000000u) ? ~b : (b | 0x80000000u);
}
__device__ __forceinline__ float key2f(unsigned k) {
  return (k & 0x80000000u) ? __uint_as_float(k & 0x7FFFFFFFu) : __uint_as_float(~k);
}

// ---------- combined transpose for x and ctx (one launch) ----------
// x:[256][2048]->xT[2048][256], ctx:[256][1024]->ctxT[1024][256]
__global__ __launch_bounds__(256) void transpose2_k(const float* __restrict__ xsrc,
                                                    float* __restrict__ xdst,
                                                    const float* __restrict__ csrc,
                                                    float* __restrict__ cdst) {
  __shared__ float tile[32][33];
  int bid = blockIdx.x;
  const float* src; float* dst; int cols;
  const int NX = (D_IN / 32) * (B_SZ / 32);  // 512
  if (bid < NX) { src = xsrc; dst = xdst; cols = D_IN; }
  else { bid -= NX; src = csrc; dst = cdst; cols = D_CTX; }
  int nbx = cols / 32;
  int bx = bid % nbx, by = bid / nbx;
  int c0 = bx * 32, r0 = by * 32;
  int tx = threadIdx.x & 31, ty = threadIdx.x >> 5;
  for (int i = ty; i < 32; i += 8)
    tile[i][tx] = src[(r0 + i) * cols + (c0 + tx)];
  __syncthreads();
  for (int i = ty; i < 32; i += 8)
    dst[(c0 + i) * B_SZ + (r0 + tx)] = tile[tx][i];
}

// ---------- wave-local compaction (NO barriers: per-wave buffer, in-order wave) ----------
__device__ __forceinline__ int compact_wave(const float* __restrict__ wrow,
                                            const float* __restrict__ mrow,
                                            int len4, float2* pairs, int* scnt) {
  const int t = threadIdx.x & 63;
  if (t == 0) *scnt = 0;
  __builtin_amdgcn_wave_barrier();
  for (int e = t; e < len4; e += 64) {
    f32x4 w = ntld4(wrow + 4 * e);
    f32x4 m = ntld4(mrow + 4 * e);
    bool n0 = (m.x != 0.f), n1 = (m.y != 0.f), n2 = (m.z != 0.f), n3 = (m.w != 0.f);
    int nz = (int)n0 + (int)n1 + (int)n2 + (int)n3;
    if (nz) {
      int pos = atomicAdd(scnt, nz);
      int c = e << 2;
      if (n0) { if (pos < CAP) pairs[pos] = make_float2(w.x, __int_as_float(c));     pos++; }
      if (n1) { if (pos < CAP) pairs[pos] = make_float2(w.y, __int_as_float(c + 1)); pos++; }
      if (n2) { if (pos < CAP) pairs[pos] = make_float2(w.z, __int_as_float(c + 2)); pos++; }
      if (n3) { if (pos < CAP) pairs[pos] = make_float2(w.w, __int_as_float(c + 3)); pos++; }
    }
  }
  __builtin_amdgcn_wave_barrier();
  int c = *scnt;
  return c > CAP ? CAP : c;
}

// store prefetched regs (one D_CTX seg row) into pair buffer; wave-local
__device__ __forceinline__ int store_seg(const f32x4 w[4], const f32x4 m[4],
                                         float2* pairs, int* scnt) {
  const int t = threadIdx.x & 63;
  if (t == 0) *scnt = 0;
  __builtin_amdgcn_wave_barrier();
#pragma unroll
  for (int i = 0; i < 4; ++i) {
    int e = t + 64 * i;
    f32x4 ww = w[i], mm = m[i];
    bool n0 = (mm.x != 0.f), n1 = (mm.y != 0.f), n2 = (mm.z != 0.f), n3 = (mm.w != 0.f);
    int nz = (int)n0 + (int)n1 + (int)n2 + (int)n3;
    if (nz) {
      int pos = atomicAdd(scnt, nz);
      int c = e << 2;
      if (n0) { if (pos < CAP) pairs[pos] = make_float2(ww.x, __int_as_float(c));     pos++; }
      if (n1) { if (pos < CAP) pairs[pos] = make_float2(ww.y, __int_as_float(c + 1)); pos++; }
      if (n2) { if (pos < CAP) pairs[pos] = make_float2(ww.z, __int_as_float(c + 2)); pos++; }
      if (n3) { if (pos < CAP) pairs[pos] = make_float2(ww.w, __int_as_float(c + 3)); pos++; }
    }
  }
  __builtin_amdgcn_wave_barrier();
  int c = *scnt;
  return c > CAP ? CAP : c;
}

__device__ __forceinline__ void load_seg(const float* __restrict__ wrow,
                                         const float* __restrict__ mrow,
                                         f32x4 w[4], f32x4 m[4]) {
  const int t = threadIdx.x & 63;
#pragma unroll
  for (int i = 0; i < 4; ++i) {
    w[i] = ntld4(wrow + 4 * (t + 64 * i));
    m[i] = ntld4(mrow + 4 * (t + 64 * i));
  }
}

// ---------- sparse dot, unroll-8 (8 outstanding 1KB loads/wave) ----------
__device__ __forceinline__ void gather_dot(const float* __restrict__ src,
                                           const float2* pairs, int cnt,
                                           int t4, float out4[4]) {
  float acc[4][4];
#pragma unroll
  for (int s = 0; s < 4; ++s)
#pragma unroll
    for (int i = 0; i < 4; ++i) acc[s][i] = 0.f;
  int j = 0;
  for (; j + 8 <= cnt; j += 8) {
#pragma unroll
    for (int s = 0; s < 8; ++s) {
      float2 p = pairs[j + s];
      const f32x4 cv = *(const f32x4*)(src + (__float_as_int(p.y) << 8) + t4);
      acc[s & 3][0] += cv.x * p.x; acc[s & 3][1] += cv.y * p.x;
      acc[s & 3][2] += cv.z * p.x; acc[s & 3][3] += cv.w * p.x;
    }
  }
  for (; j < cnt; ++j) {
    float2 p = pairs[j];
    const f32x4 cv = *(const f32x4*)(src + (__float_as_int(p.y) << 8) + t4);
    acc[0][0] += cv.x * p.x; acc[0][1] += cv.y * p.x;
    acc[0][2] += cv.z * p.x; acc[0][3] += cv.w * p.x;
  }
#pragma unroll
  for (int i = 0; i < 4; ++i)
    out4[i] = (acc[0][i] + acc[1][i]) + (acc[2][i] + acc[3][i]);
}

// ---------- dendrite kernel: 4 independent waves/block, one row per wave ----------
// Pipeline: prefetch seg s+1 weights into regs (issue-only), gather seg s, then
// mask-test/store the regs to LDS. vmcnt FIFO => prefetch has landed by then.
__global__ __launch_bounds__(256, 3) void dend_kernel(
    const float* __restrict__ W1, const float* __restrict__ maskW1, const float* __restrict__ b1,
    const float* __restrict__ segW1, const float* __restrict__ maskS1,
    const float* __restrict__ segW2, const float* __restrict__ maskS2,
    const float* __restrict__ xT, const float* __restrict__ ctxT,
    float* __restrict__ y1T, float* __restrict__ gate2T) {
  __shared__ float2 pairs_s[4][CAP];
  __shared__ int scnt_s[4];
  const int wave = threadIdx.x >> 6;
  const int t = threadIdx.x & 63, t4 = t * 4;
  float2* pairs = pairs_s[wave];
  int* scnt = &scnt_s[wave];
  const int row = blockIdx.x * 4 + wave;

  const bool isL1 = (row < HID);
  const int u = isL1 ? row : (row - HID);
  const float* segW = (isL1 ? segW1 : segW2) + (size_t)u * NSEG * D_CTX;
  const float* maskS = (isL1 ? maskS1 : maskS2) + (size_t)u * NSEG * D_CTX;

  float bestA[4] = {-1.f, -1.f, -1.f, -1.f};
  float chosen[4] = {0.f, 0.f, 0.f, 0.f};
  float ff[4] = {0.f, 0.f, 0.f, 0.f};

  f32x4 w[4], m[4];
  if (isL1) {
    // FF row: compact (stalls on HBM once), prefetch seg0, then FF gather
    int cnt = compact_wave(W1 + (size_t)u * D_IN, maskW1 + (size_t)u * D_IN,
                           D_IN / 4, pairs, scnt);
    load_seg(segW, maskS, w, m);
    gather_dot(xT, pairs, cnt, t4, ff);
  } else {
    load_seg(segW, maskS, w, m);
  }

  for (int s = 0; s < NSEG; ++s) {
    int cnt = store_seg(w, m, pairs, scnt);   // waits on prefetch (already landed for s>0)
    if (s + 1 < NSEG)
      load_seg(segW + (s + 1) * D_CTX, maskS + (s + 1) * D_CTX, w, m);  // issue-only
    float d[4];
    gather_dot(ctxT, pairs, cnt, t4, d);
#pragma unroll
    for (int i = 0; i < 4; ++i) {
      float a = fabsf(d[i]);
      if (a > bestA[i]) { bestA[i] = a; chosen[i] = d[i]; }  // strict > == first-occurrence
    }
  }

  if (isL1) {
    float bb = b1[u];
    float4 o;
    o.x = (ff[0] + bb) / (1.f + expf(-chosen[0]));
    o.y = (ff[1] + bb) / (1.f + expf(-chosen[1]));
    o.z = (ff[2] + bb) / (1.f + expf(-chosen[2]));
    o.w = (ff[3] + bb) / (1.f + expf(-chosen[3]));
    *(float4*)(y1T + (size_t)u * B_SZ + t4) = o;
  } else {
    float4 g;
    g.x = 1.f / (1.f + expf(-chosen[0]));
    g.y = 1.f / (1.f + expf(-chosen[1]));
    g.z = 1.f / (1.f + expf(-chosen[2]));
    g.w = 1.f / (1.f + expf(-chosen[3]));
    *(float4*)(gate2T + (size_t)u * B_SZ + t4) = g;
  }
}

// ---------- FF2: 4 independent waves/block, one u per wave, no barriers ----------
__global__ __launch_bounds__(256, 4) void ff2_kernel(
    const float* __restrict__ W2, const float* __restrict__ maskW2, const float* __restrict__ b2,
    const float* __restrict__ h1T, const float* __restrict__ gate2T, float* __restrict__ y2T) {
  __shared__ float2 pairs_s[4][CAP];
  __shared__ int scnt_s[4];
  const int wave = threadIdx.x >> 6;
  const int t = threadIdx.x & 63, t4 = t * 4;
  const int u = blockIdx.x * 4 + wave;
  int cnt = compact_wave(W2 + (size_t)u * HID, maskW2 + (size_t)u * HID,
                         HID / 4, pairs_s[wave], &scnt_s[wave]);
  float acc[4];
  gather_dot(h1T, pairs_s[wave], cnt, t4, acc);
  float bb = b2[u];
  float4 g = *(const float4*)(gate2T + (size_t)u * B_SZ + t4);
  float4 o;
  o.x = (acc[0] + bb) * g.x; o.y = (acc[1] + bb) * g.y;
  o.z = (acc[2] + bb) * g.z; o.w = (acc[3] + bb) * g.w;
  *(float4*)(y2T + (size_t)u * B_SZ + t4) = o;
}

// ---------- exact top-K per batch column of yT [HID][B]; radix select, stable ties ----------
// mode 0: write in place (same [HID][B] layout); mode 1: write rows dst[b][HID]
__global__ __launch_bounds__(256) void topk_kernel(const float* __restrict__ yT,
                                                   float* __restrict__ dst, int mode) {
  const int b = blockIdx.x, t = threadIdx.x;
  __shared__ int hist[256];
  __shared__ int sfx[256];
  __shared__ unsigned sPref;
  __shared__ int sRem;
  unsigned myk[8];
#pragma unroll
  for (int i = 0; i < 8; ++i)
    myk[i] = f2key(yT[(size_t)(t * 8 + i) * B_SZ + b]);  // contiguous u per thread: index order
  unsigned pref = 0;
  int rem = KWIN;
  for (int shift = 24; shift >= 0; shift -= 8) {
    hist[t] = 0;
    __syncthreads();
    unsigned hiMask = (shift == 24) ? 0u : (0xFFFFFFFFu << (shift + 8));
#pragma unroll
    for (int i = 0; i < 8; ++i) {
      unsigned k = myk[i];
      if ((k & hiMask) == pref) atomicAdd(&hist[(k >> shift) & 255], 1);
    }
    __syncthreads();
    sfx[t] = hist[t];
    __syncthreads();
    for (int off = 1; off < 256; off <<= 1) {
      int add = (t + off < 256) ? sfx[t + off] : 0;
      __syncthreads();
      sfx[t] += add;
      __syncthreads();
    }
    int s_incl = sfx[t];
    int s_excl = (t == 255) ? 0 : sfx[t + 1];
    if (s_incl >= rem && s_excl < rem) {
      sPref = pref | (((unsigned)t) << shift);
      sRem = rem - s_excl;
    }
    __syncthreads();
    pref = sPref;
    rem = sRem;
    __syncthreads();
  }
  int eq = 0;
#pragma unroll
  for (int i = 0; i < 8; ++i) eq += (myk[i] == pref) ? 1 : 0;
  sfx[t] = eq;
  __syncthreads();
  for (int off = 1; off < 256; off <<= 1) {
    int add = (t >= off) ? sfx[t - off] : 0;
    __syncthreads();
    sfx[t] += add;
    __syncthreads();
  }
  int excl = sfx[t] - eq;
  int taken = 0;
#pragma unroll
  for (int i = 0; i < 8; ++i) {
    unsigned k = myk[i];
    bool keep;
    if (k > pref) keep = true;
    else if (k == pref) { keep = (excl + taken) < rem; taken++; }
    else keep = false;
    float f = keep ? key2f(k) : 0.f;
    int uu = t * 8 + i;
    if (mode == 0) dst[(size_t)uu * B_SZ + b] = f;
    else dst[(size_t)b * HID + uu] = f;
  }
}

// ---------- Dale output head: out[b,o] = h2.Wex[o] - Wei[o]*(h2.Wix) + b_out[o] ----------
__global__ __launch_bounds__(256) void out_kernel(
    const float* __restrict__ h2, const float* __restrict__ Wex, const float* __restrict__ Wix,
    const float* __restrict__ Wei, const float* __restrict__ bo, float* __restrict__ out) {
  const int b = blockIdx.x, t = threadIdx.x;
  __shared__ float hrow[HID];
  __shared__ float red[256];
  float part = 0.f;
#pragma unroll
  for (int i = 0; i < 8; ++i) {
    int u = t + 256 * i;
    float v = h2[(size_t)b * HID + u];
    hrow[u] = v;
    part += v * Wix[u];
  }
  red[t] = part;
  __syncthreads();
  for (int off = 128; off > 0; off >>= 1) {
    if (t < off) red[t] += red[t + off];
    __syncthreads();
  }
  float S = red[0];
  const int w = t >> 6, l = t & 63;
  for (int o = w; o < OUT_N; o += 4) {
    float acc = 0.f;
    const float* wr = Wex + (size_t)o * HID;
#pragma unroll
    for (int q = 0; q < HID / 64; ++q) acc += hrow[l + 64 * q] * wr[l + 64 * q];
    for (int off = 32; off > 0; off >>= 1) acc += __shfl_down(acc, off, 64);
    if (l == 0) out[(size_t)b * OUT_N + o] = acc - Wei[o] * S + bo[o];
  }
}

extern "C" void kernel_launch(void* const* d_in, const int* in_sizes, int n_in,
                              void* d_out, int out_size, void* d_ws, size_t ws_size,
                              hipStream_t stream) {
  const float* x      = (const float*)d_in[0];
  const float* ctx    = (const float*)d_in[1];
  const float* W1     = (const float*)d_in[2];
  const float* b1     = (const float*)d_in[3];
  const float* segW1  = (const float*)d_in[4];
  const float* maskW1 = (const float*)d_in[5];
  const float* maskS1 = (const float*)d_in[6];
  const float* W2     = (const float*)d_in[7];
  const float* b2     = (const float*)d_in[8];
  const float* segW2  = (const float*)d_in[9];
  const float* maskW2 = (const float*)d_in[10];
  const float* maskS2 = (const float*)d_in[11];
  const float* Wex    = (const float*)d_in[12];
  const float* Wix    = (const float*)d_in[13];
  const float* Wei    = (const float*)d_in[14];
  const float* bo     = (const float*)d_in[15];
  float* out = (float*)d_out;
  float* ws = (float*)d_ws;

  float* xT     = ws;             // 524288 floats
  float* ctxT   = ws + 524288;    // 262144
  float* y1T    = ws + 786432;    // 524288 (becomes h1T in place)
  float* gate2T = ws + 1310720;   // 524288
  float* y2T    = ws + 1835008;   // 524288
  float* h2     = ws + 2359296;   // 524288 (row-major) — total ~11.5 MB

  transpose2_k<<<768, 256, 0, stream>>>(x, xT, ctx, ctxT);
  dend_kernel<<<2 * HID / 4, 256, 0, stream>>>(W1, maskW1, b1, segW1, maskS1, segW2, maskS2,
                                               xT, ctxT, y1T, gate2T);
  topk_kernel<<<B_SZ, 256, 0, stream>>>(y1T, y1T, 0);   // h1T in place
  ff2_kernel<<<HID / 4, 256, 0, stream>>>(W2, maskW2, b2, y1T, gate2T, y2T);
  topk_kernel<<<B_SZ, 256, 0, stream>>>(y2T, h2, 1);    // h2 rows
  out_kernel<<<B_SZ, 256, 0, stream>>>(h2, Wex, Wix, Wei, bo, out);
}